// Round 15
// baseline (309.437 us; speedup 1.0000x reference)
//
#include <hip/hip_runtime.h>
#include <hip/hip_bf16.h>

// Problem constants (fixed by reference): B=4, S=2048, DIN=DOUT=4096
constexpr int GM = 8192;   // B*S rows
constexpr int GN = 4096;   // DOUT
constexpr int GK = 4096;   // DIN

constexpr int BM = 256, BN = 256, BK = 64;
constexpr int NSTEP = GK / BK;   // 64 K-steps
constexpr int IT = NSTEP / 2;    // 32 iterations, 2 K-steps each
constexpr int LDS_BYTES = 2 * (BM + BN) * BK * 2;  // 131072 = 128 KiB

using bf16x8 = __attribute__((ext_vector_type(8))) __bf16;
using f32x4  = __attribute__((ext_vector_type(4))) float;

// -------------------- prep: A = bf16(x * in_scale) --------------------
__global__ __launch_bounds__(256) void prep_x_kernel(
    const float* __restrict__ x, const float* __restrict__ iscale,
    __bf16* __restrict__ A) {
  int e = (blockIdx.x * 256 + threadIdx.x) * 8;  // 8 elems/thread
  float4 v0 = *(const float4*)(x + e);
  float4 v1 = *(const float4*)(x + e + 4);
  int k = e & (GK - 1);
  float4 s0 = *(const float4*)(iscale + k);
  float4 s1 = *(const float4*)(iscale + k + 4);
  bf16x8 o;
  o[0] = (__bf16)(v0.x * s0.x);
  o[1] = (__bf16)(v0.y * s0.y);
  o[2] = (__bf16)(v0.z * s0.z);
  o[3] = (__bf16)(v0.w * s0.w);
  o[4] = (__bf16)(v1.x * s1.x);
  o[5] = (__bf16)(v1.y * s1.y);
  o[6] = (__bf16)(v1.z * s1.z);
  o[7] = (__bf16)(v1.w * s1.w);
  *(bf16x8*)(A + e) = o;
}

// -------------------- prep: Wb = bf16(sign(W)) --------------------
__device__ inline float sgnf(float v) {
  return (float)((v > 0.f) - (v < 0.f));
}

__global__ __launch_bounds__(256) void prep_w_kernel(
    const float* __restrict__ w, __bf16* __restrict__ Wb) {
  int e = (blockIdx.x * 256 + threadIdx.x) * 8;
  float4 v0 = *(const float4*)(w + e);
  float4 v1 = *(const float4*)(w + e + 4);
  bf16x8 o;
  o[0] = (__bf16)sgnf(v0.x);
  o[1] = (__bf16)sgnf(v0.y);
  o[2] = (__bf16)sgnf(v0.z);
  o[3] = (__bf16)sgnf(v0.w);
  o[4] = (__bf16)sgnf(v1.x);
  o[5] = (__bf16)sgnf(v1.y);
  o[6] = (__bf16)sgnf(v1.z);
  o[7] = (__bf16)sgnf(v1.w);
  *(bf16x8*)(Wb + e) = o;
}

// -------------------- GEMM: C[m][n] = sum_k A[m][k]*Wb[n][k] --------------------
// R14 base with READ-ONE-QUAD-AHEAD: each phase's ds_reads feed the NEXT
// phase's quad, and the manual lgkmcnt(0) is removed — the compiler emits
// counted lgkm waits before first use (reads are plain C++ loads), which
// now retire pre-drained because the reads had a full phase (~1100 cyc) of
// MFMA window to complete. This converts the phase-serial LDS->MFMA
// alternation (R3-R14's ~51% plateau: all waves stall on lgkmcnt(0) while
// the LDS pipe drains with the MFMA pipe idle) into pipe overlap.
// Read schedule: prologue/P8 read a0,b0; P1: Q00 + read b2; P2: Q02 + read
// a4; P3: Q40 + vmcnt(4); P4: Q42 + read next-step a0,b0 (safe: that
// buffer was certified by P3-end's vmcnt+barrier); P5-P8 mirror.
// vmcnt(4) retire-sets (re-derived): P3-end queue = [o:B0B1(prevP7,4),
// o:A0(prevP8,2), o:A1(P1,2), n0:B0B1(P3,4)] -> retires exactly step o;
// P7-end queue = [n0:B0B1(P3,4), n0:A0(P4,2), n0:A1(P5,2), n1:B0B1(P7,4)]
// -> retires exactly n0 before P8 reads buf0. WAR: every region's reads
// complete via compiler auto-wait before that wave's same-phase MFMA,
// hence before the phase-end barrier preceding any re-stage.
// Swizzle (both sides, 0 conflicts measured R3-R14): 16-B chunk c of row r
// holds K-group c^(r&7). Epilogue: bf16 h into 2nd half of each f32 row
// slot (R13). XCD chunking: FETCH ~197 MB.
__device__ inline void gload16(const __bf16* g, const __bf16* l) {
  __builtin_amdgcn_global_load_lds(
      (const __attribute__((address_space(1))) void*)g,
      (__attribute__((address_space(3))) void*)l, 16, 0, 0);
}

#define PHASE_MFMA(AV, BV, MO, NO)                      \
  __builtin_amdgcn_sched_barrier(0);                    \
  __builtin_amdgcn_s_barrier();                         \
  __builtin_amdgcn_s_setprio(1);                        \
  QUAD(AV, BV, MO, NO);                                 \
  __builtin_amdgcn_s_setprio(0);

#define QUAD(AV, BV, MO, NO)                                                 \
  {                                                                          \
    _Pragma("unroll") for (int kk = 0; kk < 2; ++kk)                         \
      _Pragma("unroll") for (int mi = 0; mi < 4; ++mi)                       \
        _Pragma("unroll") for (int ni = 0; ni < 2; ++ni)                     \
            acc[(MO) + mi][(NO) + ni] =                                      \
                __builtin_amdgcn_mfma_f32_16x16x32_bf16(                     \
                    AV[mi][kk], BV[ni][kk], acc[(MO) + mi][(NO) + ni],       \
                    0, 0, 0);                                                \
  }

__global__ __launch_bounds__(512, 2) void gemm_bt(
    const __bf16* __restrict__ A, const __bf16* __restrict__ B,
    float* __restrict__ C) {
  extern __shared__ __bf16 lds[];  // 2 x 64 KiB buffers

  // Square XCD chunking (FETCH ~197 MB measured R3-R14)
  int bid = blockIdx.x;            // 0..511
  int x = bid & 7, idx = bid >> 3;
  int brow = ((x & 3) << 3) | (idx & 7);   // 0..31
  int bcol = ((x >> 2) << 3) | (idx >> 3); // 0..15

  int tid = threadIdx.x, wid = tid >> 6, lane = tid & 63;
  int wm = wid & 1, wn = wid >> 1;         // 2M x 4N waves
  int lrow = lane & 15, lkhi = lane >> 4;

  const __bf16* Ab = A + (size_t)(brow * BM) * GK;
  const __bf16* Bb = B + (size_t)(bcol * BN) * GK;
  const __bf16* Ab1 = Ab + (size_t)128 * GK;
  const __bf16* Bb1 = Bb + (size_t)128 * GK;

  // read-side swizzled chunk offsets (bytes within the 128-B row)
  int xr = lrow & 7;
  int offk0 = (lkhi ^ xr) * 16;        // kk=0 chunk
  int offk1 = ((4 + lkhi) ^ xr) * 16;  // kk=1 chunk
  const char* ldsc = (const char*)lds;
  // fragment byte bases within a buffer (regions: A0 0, A1 16K, B0 32K, B1 48K)
  int avbase = wm * 16384 + lrow * 128;                                // +mi*2048
  int bvbase = 32768 + (wn >> 1) * 16384 + ((wn & 1) * 64 + lrow) * 128;  // +ni*2048

  // stage-side: thread t writes bytes [t*16,t*16+16) of each 8-KiB half-region
  int grow = tid >> 3;                         // row within 64-row half
  int gcol = ((tid & 7) ^ (grow & 7)) * 8;     // pre-swizzled source col (elems)

  // stage ONE 128-row half-tile (2 x gload_lds) of K-step `kstep`
  auto STAGE = [&](const __bf16* srcbase, int kstep, int dstelem) {
    const __bf16* s = srcbase + (size_t)grow * GK + kstep * BK + gcol;
    const __bf16* d = lds + dstelem + tid * 8;
    gload16(s, d);
    gload16(s + (size_t)64 * GK, d + 4096);
  };

  f32x4 acc[8][4] = {};
  bf16x8 a0[4][2], a4[4][2], b0[2][2], b2[2][2];  // live across phases

  auto RD_A0 = [&](int cb) {
#pragma unroll
    for (int mi = 0; mi < 4; ++mi) {
      a0[mi][0] = *(const bf16x8*)(ldsc + cb + avbase + mi * 2048 + offk0);
      a0[mi][1] = *(const bf16x8*)(ldsc + cb + avbase + mi * 2048 + offk1);
    }
  };
  auto RD_A4 = [&](int cb) {
#pragma unroll
    for (int mi = 0; mi < 4; ++mi) {
      a4[mi][0] = *(const bf16x8*)(ldsc + cb + avbase + (4 + mi) * 2048 + offk0);
      a4[mi][1] = *(const bf16x8*)(ldsc + cb + avbase + (4 + mi) * 2048 + offk1);
    }
  };
  auto RD_B0 = [&](int cb) {
#pragma unroll
    for (int ni = 0; ni < 2; ++ni) {
      b0[ni][0] = *(const bf16x8*)(ldsc + cb + bvbase + ni * 2048 + offk0);
      b0[ni][1] = *(const bf16x8*)(ldsc + cb + bvbase + ni * 2048 + offk1);
    }
  };
  auto RD_B2 = [&](int cb) {
#pragma unroll
    for (int ni = 0; ni < 2; ++ni) {
      b2[ni][0] = *(const bf16x8*)(ldsc + cb + bvbase + (2 + ni) * 2048 + offk0);
      b2[ni][1] = *(const bf16x8*)(ldsc + cb + bvbase + (2 + ni) * 2048 + offk1);
    }
  };

  // prologue: step0 (8 loads) -> buf0; step1 {B0,B1,A0} (6 loads) -> buf1;
  // vmcnt(6) retires step0; then pre-read step0's a0,b0 (consumed in P1/P2).
  STAGE(Ab, 0, 0);
  STAGE(Ab1, 0, 8192);
  STAGE(Bb, 0, 16384);
  STAGE(Bb1, 0, 24576);
  STAGE(Bb, 1, 49152);        // buf1:B0
  STAGE(Bb1, 1, 57344);       // buf1:B1
  STAGE(Ab, 1, 32768);        // buf1:A0
  asm volatile("s_waitcnt vmcnt(6)" ::: "memory");
  __builtin_amdgcn_s_barrier();
  RD_A0(0);
  RD_B0(0);

  for (int j = 0; j < IT; ++j) {
    int o = 2 * j + 1, n0 = 2 * j + 2, n1 = 2 * j + 3;
    bool full = (j < IT - 1);

    // ---- P1: Q00(buf0) on prefetched a0,b0; read b2<-buf0; stage o:A1
    STAGE(Ab1, o, 40960);
    RD_B2(0);
    PHASE_MFMA(a0, b0, 0, 0);
    __builtin_amdgcn_s_barrier();

    // ---- P2: Q02(buf0); read a4<-buf0
    RD_A4(0);
    PHASE_MFMA(a0, b2, 0, 2);
    __builtin_amdgcn_s_barrier();

    // ---- P3: Q40(buf0); stage n0:B0,B1 -> buf0; vmcnt(4) certifies step o
    if (full) { STAGE(Bb, n0, 16384); STAGE(Bb1, n0, 24576); }
    PHASE_MFMA(a4, b0, 4, 0);
    if (full) asm volatile("s_waitcnt vmcnt(4)" ::: "memory");
    else      asm volatile("s_waitcnt vmcnt(0)" ::: "memory");
    __builtin_amdgcn_s_barrier();

    // ---- P4: Q42(buf0); read next-step a0,b0 <- buf1 (certified); stage n0:A0
    if (full) STAGE(Ab, n0, 0);
    RD_A0(65536);
    RD_B0(65536);
    PHASE_MFMA(a4, b2, 4, 2);
    __builtin_amdgcn_s_barrier();

    // ---- P5: Q00(buf1); read b2<-buf1; stage n0:A1 -> buf0
    if (full) STAGE(Ab1, n0, 8192);
    RD_B2(65536);
    PHASE_MFMA(a0, b0, 0, 0);
    __builtin_amdgcn_s_barrier();

    // ---- P6: Q02(buf1); read a4<-buf1
    RD_A4(65536);
    PHASE_MFMA(a0, b2, 0, 2);
    __builtin_amdgcn_s_barrier();

    // ---- P7: Q40(buf1); stage n1:B0,B1 -> buf1; vmcnt(4) certifies n0
    if (full) { STAGE(Bb, n1, 49152); STAGE(Bb1, n1, 57344); }
    PHASE_MFMA(a4, b0, 4, 0);
    if (full) asm volatile("s_waitcnt vmcnt(4)" ::: "memory");
    else      asm volatile("s_waitcnt vmcnt(0)" ::: "memory");
    __builtin_amdgcn_s_barrier();

    // ---- P8: Q42(buf1); read next-step a0,b0 <- buf0; stage n1:A0 -> buf1
    if (full) {
      STAGE(Ab, n1, 32768);
      RD_A0(0);
      RD_B0(0);
    }
    PHASE_MFMA(a4, b2, 4, 2);
    __builtin_amdgcn_s_barrier();
  }

  // epilogue: h as bf16 into the second half of each f32 output row slot.
  // C/D layout (16x16x32 bf16): col = lane&15, row = (lane>>4)*4 + r
  int crow0 = brow * BM + wm * 128;
  int ccol0 = bcol * BN + wn * 64;
  char* Cb = (char*)C;
#pragma unroll
  for (int mi = 0; mi < 8; ++mi)
#pragma unroll
    for (int ni = 0; ni < 4; ++ni) {
      int col = ccol0 + ni * 16 + lrow;
#pragma unroll
      for (int r = 0; r < 4; ++r) {
        int row = crow0 + mi * 16 + lkhi * 4 + r;
        *(__bf16*)(Cb + (size_t)row * 16384 + 8192 + col * 2) =
            (__bf16)acc[mi][ni][r];
      }
    }
}

// ---------- fused out_scale/bias + LayerNorm: bf16 h (2nd half-slot) -> f32 ----------
__global__ __launch_bounds__(256) void ln_fuse(
    float* __restrict__ out, const float* __restrict__ os,
    const float* __restrict__ bs, const float* __restrict__ g,
    const float* __restrict__ be) {
  constexpr int N = GN;  // 4096
  int row = blockIdx.x;
  const __bf16* hr = (const __bf16*)((const char*)out + (size_t)row * 16384 + 8192);
  float* orow = out + (size_t)row * N;
  int t = threadIdx.x;

  float v[16];
  float sum = 0.f, ssq = 0.f;
#pragma unroll
  for (int c = 0; c < 2; ++c) {
    int idx = c * 2048 + t * 8;       // 8 bf16 per chunk, 2 chunks/thread
    bf16x8 hv = *(const bf16x8*)(hr + idx);
    float4 s0 = *(const float4*)(os + idx);
    float4 s1 = *(const float4*)(os + idx + 4);
    float4 b0 = *(const float4*)(bs + idx);
    float4 b1 = *(const float4*)(bs + idx + 4);
#pragma unroll
    for (int j = 0; j < 4; ++j) {
      float a = (float)hv[j] * (&s0.x)[j] + (&b0.x)[j];
      v[c * 8 + j] = a;
      sum += a; ssq += a * a;
    }
#pragma unroll
    for (int j = 0; j < 4; ++j) {
      float a = (float)hv[4 + j] * (&s1.x)[j] + (&b1.x)[j];
      v[c * 8 + 4 + j] = a;
      sum += a; ssq += a * a;
    }
  }

  // wave64 reduce
#pragma unroll
  for (int off = 32; off > 0; off >>= 1) {
    sum += __shfl_down(sum, off);
    ssq += __shfl_down(ssq, off);
  }
  __shared__ float rs[8];
  int wid = t >> 6, lane = t & 63;
  if (lane == 0) { rs[wid] = sum; rs[4 + wid] = ssq; }
  __syncthreads();   // also separates all h reads from the in-place writes
  sum = rs[0] + rs[1] + rs[2] + rs[3];
  ssq = rs[4] + rs[5] + rs[6] + rs[7];

  float mean = sum * (1.f / N);
  float var = ssq * (1.f / N) - mean * mean;
  float rstd = rsqrtf(var + 1e-5f);

#pragma unroll
  for (int c = 0; c < 2; ++c) {
    int idx = c * 2048 + t * 8;
    float4 g0 = *(const float4*)(g + idx);
    float4 g1 = *(const float4*)(g + idx + 4);
    float4 e0 = *(const float4*)(be + idx);
    float4 e1 = *(const float4*)(be + idx + 4);
    float4 o0, o1;
#pragma unroll
    for (int j = 0; j < 4; ++j) {
      (&o0.x)[j] = (v[c * 8 + j] - mean) * rstd * (&g0.x)[j] + (&e0.x)[j];
      (&o1.x)[j] = (v[c * 8 + 4 + j] - mean) * rstd * (&g1.x)[j] + (&e1.x)[j];
    }
    *(float4*)(orow + idx) = o0;
    *(float4*)(orow + idx + 4) = o1;
  }
}

extern "C" void kernel_launch(void* const* d_in, const int* in_sizes, int n_in,
                              void* d_out, int out_size, void* d_ws, size_t ws_size,
                              hipStream_t stream) {
  const float* x      = (const float*)d_in[0];  // [4,2048,4096]
  const float* w      = (const float*)d_in[1];  // [4096,4096]
  const float* iscale = (const float*)d_in[2];  // [4096]
  const float* oscale = (const float*)d_in[3];  // [4096]
  const float* bias   = (const float*)d_in[4];  // [4096]
  const float* gamma  = (const float*)d_in[5];  // [4096]
  const float* beta   = (const float*)d_in[6];  // [4096]
  float* out = (float*)d_out;                   // [8192,4096] f32

  __bf16* Abf = (__bf16*)d_ws;                                   // 67 MB
  __bf16* Wbf = (__bf16*)((char*)d_ws + (size_t)GM * GK * 2);    // 33.5 MB

  (void)hipFuncSetAttribute((const void*)gemm_bt,
                            hipFuncAttributeMaxDynamicSharedMemorySize, LDS_BYTES);

  prep_x_kernel<<<(GM * GK) / (256 * 8), 256, 0, stream>>>(x, iscale, Abf);
  prep_w_kernel<<<(GN * GK) / (256 * 8), 256, 0, stream>>>(w, Wbf);
  gemm_bt<<<(GM / BM) * (GN / BN), 512, LDS_BYTES, stream>>>(Abf, Wbf, out);
  ln_fuse<<<GM, 256, 0, stream>>>(out, oscale, bias, gamma, beta);
}

// Round 16
// 293.479 us; speedup vs baseline: 1.0544x; 1.0544x over previous
//
#include <hip/hip_runtime.h>
#include <hip/hip_bf16.h>

// Problem constants (fixed by reference): B=4, S=2048, DIN=DOUT=4096
constexpr int GM = 8192;   // B*S rows
constexpr int GN = 4096;   // DOUT
constexpr int GK = 4096;   // DIN

constexpr int BM = 256, BN = 256, BK = 64;
constexpr int NSTEP = GK / BK;   // 64 K-steps
constexpr int IT = NSTEP / 2;    // 32 iterations, 2 K-steps each
constexpr int LDS_BYTES = 2 * (BM + BN) * BK * 2;  // 131072 = 128 KiB

constexpr int PX_BLOCKS = (GM * GK) / (256 * 8);   // 16384
constexpr int PW_BLOCKS = (GN * GK) / (256 * 8);   // 8192

using bf16x8 = __attribute__((ext_vector_type(8))) __bf16;
using f32x4  = __attribute__((ext_vector_type(4))) float;

// ---------- fused prep: A = bf16(x*in_scale)  |  Wb = bf16(sign(w)) ----------
__device__ inline float sgnf(float v) {
  return (float)((v > 0.f) - (v < 0.f));
}

__global__ __launch_bounds__(256) void prep_fused(
    const float* __restrict__ x, const float* __restrict__ iscale,
    const float* __restrict__ w, __bf16* __restrict__ A,
    __bf16* __restrict__ Wb) {
  int b = blockIdx.x;
  if (b < PX_BLOCKS) {
    int e = (b * 256 + threadIdx.x) * 8;
    float4 v0 = *(const float4*)(x + e);
    float4 v1 = *(const float4*)(x + e + 4);
    int k = e & (GK - 1);
    float4 s0 = *(const float4*)(iscale + k);
    float4 s1 = *(const float4*)(iscale + k + 4);
    bf16x8 o;
    o[0] = (__bf16)(v0.x * s0.x);
    o[1] = (__bf16)(v0.y * s0.y);
    o[2] = (__bf16)(v0.z * s0.z);
    o[3] = (__bf16)(v0.w * s0.w);
    o[4] = (__bf16)(v1.x * s1.x);
    o[5] = (__bf16)(v1.y * s1.y);
    o[6] = (__bf16)(v1.z * s1.z);
    o[7] = (__bf16)(v1.w * s1.w);
    *(bf16x8*)(A + e) = o;
  } else {
    int e = ((b - PX_BLOCKS) * 256 + threadIdx.x) * 8;
    float4 v0 = *(const float4*)(w + e);
    float4 v1 = *(const float4*)(w + e + 4);
    bf16x8 o;
    o[0] = (__bf16)sgnf(v0.x);
    o[1] = (__bf16)sgnf(v0.y);
    o[2] = (__bf16)sgnf(v0.z);
    o[3] = (__bf16)sgnf(v0.w);
    o[4] = (__bf16)sgnf(v1.x);
    o[5] = (__bf16)sgnf(v1.y);
    o[6] = (__bf16)sgnf(v1.z);
    o[7] = (__bf16)sgnf(v1.w);
    *(bf16x8*)(Wb + e) = o;
  }
}

// -------------------- GEMM: C[m][n] = sum_k A[m][k]*Wb[n][k] --------------------
// R13/R14 base with BALANCED 8/4/8/4 per-phase ds_read distribution (the
// m201 signature: "4 or 8 ds_read_b128 per phase", never 12, never 0).
// a0 is split lo(mi0-1)/hi(mi2-3): the lo half of the NEXT K-step is read
// in P4/P8 (4 reads, from the buffer certified by the vmcnt moved to
// P3/P7-end), the hi half + b0 in P1/P5 (8), b2 in P2/P6 (4), a4 in P3/P7
// (8). Per-phase LDS convoy <= 64 KB (~750 cyc) ~ MFMA window (621 cyc),
// so waves' reads and MFMAs overlap across the CU instead of alternating
// (R13's 12-read P1 = 96 KB = ~1130 cyc serial lump; R15's P4 lump same).
// vmcnt(4) retire-sets at P3/P7-end (queue: 12 outstanding = prev step's
// 8 + this phase's B0B1 4 -> retires exactly the step consumed next).
// WAR: every region's stage phase follows its last-read phase across a
// barrier (A0/A1 read by P3, staged P4/P5; B read by P2, staged P3; the
// P4/P8 aL read targets the OTHER buffer). Register sets aL_0/aL_1
// statically named (rule 20). Swizzle (0 conflicts R3-R15): chunk c of
// row r holds K-group c^(r&7), both sides. Epilogue: bf16 h into 2nd half
// of each f32 row slot (R13). XCD chunking: FETCH ~197 MB.
__device__ inline void gload16(const __bf16* g, const __bf16* l) {
  __builtin_amdgcn_global_load_lds(
      (const __attribute__((address_space(1))) void*)g,
      (__attribute__((address_space(3))) void*)l, 16, 0, 0);
}

#define PHASE_SYNC()                                    \
  __builtin_amdgcn_s_barrier();                         \
  asm volatile("s_waitcnt lgkmcnt(0)" ::: "memory");    \
  __builtin_amdgcn_sched_barrier(0);                    \
  __builtin_amdgcn_s_setprio(1);

#define PHASE_END()                                     \
  __builtin_amdgcn_s_setprio(0);                        \
  __builtin_amdgcn_s_barrier();

// half-quad: 2 mi x 2 ni x 2 kk = 8 MFMA (kk outer; numerics per-acc equal)
#define QH(AV, BV, MO, NO)                                                   \
  {                                                                          \
    _Pragma("unroll") for (int kk = 0; kk < 2; ++kk)                         \
      _Pragma("unroll") for (int mi = 0; mi < 2; ++mi)                       \
        _Pragma("unroll") for (int ni = 0; ni < 2; ++ni)                     \
            acc[(MO) + mi][(NO) + ni] =                                      \
                __builtin_amdgcn_mfma_f32_16x16x32_bf16(                     \
                    AV[mi][kk], BV[ni][kk], acc[(MO) + mi][(NO) + ni],       \
                    0, 0, 0);                                                \
  }

// full quad over 4 mi (for a4)
#define QUAD4(AV, BV, MO, NO)                                                \
  {                                                                          \
    _Pragma("unroll") for (int kk = 0; kk < 2; ++kk)                         \
      _Pragma("unroll") for (int mi = 0; mi < 4; ++mi)                       \
        _Pragma("unroll") for (int ni = 0; ni < 2; ++ni)                     \
            acc[(MO) + mi][(NO) + ni] =                                      \
                __builtin_amdgcn_mfma_f32_16x16x32_bf16(                     \
                    AV[mi][kk], BV[ni][kk], acc[(MO) + mi][(NO) + ni],       \
                    0, 0, 0);                                                \
  }

__global__ __launch_bounds__(512, 2) void gemm_bt(
    const __bf16* __restrict__ A, const __bf16* __restrict__ B,
    float* __restrict__ C) {
  extern __shared__ __bf16 lds[];  // 2 x 64 KiB buffers

  // Square XCD chunking (FETCH ~197 MB measured R3-R15)
  int bid = blockIdx.x;            // 0..511
  int x = bid & 7, idx = bid >> 3;
  int brow = ((x & 3) << 3) | (idx & 7);   // 0..31
  int bcol = ((x >> 2) << 3) | (idx >> 3); // 0..15

  int tid = threadIdx.x, wid = tid >> 6, lane = tid & 63;
  int wm = wid & 1, wn = wid >> 1;         // 2M x 4N waves
  int lrow = lane & 15, lkhi = lane >> 4;

  const __bf16* Ab = A + (size_t)(brow * BM) * GK;
  const __bf16* Bb = B + (size_t)(bcol * BN) * GK;
  const __bf16* Ab1 = Ab + (size_t)128 * GK;
  const __bf16* Bb1 = Bb + (size_t)128 * GK;

  // read-side swizzled chunk offsets (bytes within the 128-B row)
  int xr = lrow & 7;
  int offk0 = (lkhi ^ xr) * 16;        // kk=0 chunk
  int offk1 = ((4 + lkhi) ^ xr) * 16;  // kk=1 chunk
  const char* ldsc = (const char*)lds;
  // fragment byte bases within a buffer (regions: A0 0, A1 16K, B0 32K, B1 48K)
  int avbase = wm * 16384 + lrow * 128;                                // +mi*2048
  int bvbase = 32768 + (wn >> 1) * 16384 + ((wn & 1) * 64 + lrow) * 128;  // +ni*2048

  // stage-side: thread t writes bytes [t*16,t*16+16) of each 8-KiB half-region
  int grow = tid >> 3;                         // row within 64-row half
  int gcol = ((tid & 7) ^ (grow & 7)) * 8;     // pre-swizzled source col (elems)

  // stage ONE 128-row half-tile (2 x gload_lds) of K-step `kstep`
  auto STAGE = [&](const __bf16* srcbase, int kstep, int dstelem) {
    const __bf16* s = srcbase + (size_t)grow * GK + kstep * BK + gcol;
    const __bf16* d = lds + dstelem + tid * 8;
    gload16(s, d);
    gload16(s + (size_t)64 * GK, d + 4096);
  };

  f32x4 acc[8][4] = {};
  // register sets: aL_* = a0 lo-half (mi0-1) read one phase early (static
  // names per parity — rule 20); a0h = hi-half (mi2-3); a4; b0; b2.
  bf16x8 aL_0[2][2], aL_1[2][2], a0h[2][2], a4[4][2], b0[2][2], b2[2][2];

  auto RD_AL = [&](int cb, bf16x8 (&aL)[2][2]) {
#pragma unroll
    for (int mi = 0; mi < 2; ++mi) {
      aL[mi][0] = *(const bf16x8*)(ldsc + cb + avbase + mi * 2048 + offk0);
      aL[mi][1] = *(const bf16x8*)(ldsc + cb + avbase + mi * 2048 + offk1);
    }
  };
  auto RD_A0H = [&](int cb) {
#pragma unroll
    for (int mi = 0; mi < 2; ++mi) {
      a0h[mi][0] = *(const bf16x8*)(ldsc + cb + avbase + (2 + mi) * 2048 + offk0);
      a0h[mi][1] = *(const bf16x8*)(ldsc + cb + avbase + (2 + mi) * 2048 + offk1);
    }
  };
  auto RD_A4 = [&](int cb) {
#pragma unroll
    for (int mi = 0; mi < 4; ++mi) {
      a4[mi][0] = *(const bf16x8*)(ldsc + cb + avbase + (4 + mi) * 2048 + offk0);
      a4[mi][1] = *(const bf16x8*)(ldsc + cb + avbase + (4 + mi) * 2048 + offk1);
    }
  };
  auto RD_B0 = [&](int cb) {
#pragma unroll
    for (int ni = 0; ni < 2; ++ni) {
      b0[ni][0] = *(const bf16x8*)(ldsc + cb + bvbase + ni * 2048 + offk0);
      b0[ni][1] = *(const bf16x8*)(ldsc + cb + bvbase + ni * 2048 + offk1);
    }
  };
  auto RD_B2 = [&](int cb) {
#pragma unroll
    for (int ni = 0; ni < 2; ++ni) {
      b2[ni][0] = *(const bf16x8*)(ldsc + cb + bvbase + (2 + ni) * 2048 + offk0);
      b2[ni][1] = *(const bf16x8*)(ldsc + cb + bvbase + (2 + ni) * 2048 + offk1);
    }
  };

  // prologue: step0 (8 loads) -> buf0; step1 {B0,B1,A0} (6) -> buf1;
  // vmcnt(6) retires step0; pre-read step0's aL (consumed in P1/P2).
  STAGE(Ab, 0, 0);
  STAGE(Ab1, 0, 8192);
  STAGE(Bb, 0, 16384);
  STAGE(Bb1, 0, 24576);
  STAGE(Bb, 1, 49152);        // buf1:B0
  STAGE(Bb1, 1, 57344);       // buf1:B1
  STAGE(Ab, 1, 32768);        // buf1:A0
  asm volatile("s_waitcnt vmcnt(6)" ::: "memory");
  __builtin_amdgcn_s_barrier();
  RD_AL(0, aL_0);

  for (int j = 0; j < IT; ++j) {
    int o = 2 * j + 1, n0 = 2 * j + 2, n1 = 2 * j + 3;
    bool full = (j < IT - 1);

    // ====== K-step 2j (buf0) ======
    // P1: reads a0h(4)+b0(4) <- buf0; stage o:A1 -> buf1
    RD_A0H(0);
    RD_B0(0);
    STAGE(Ab1, o, 40960);
    PHASE_SYNC();
    QH(aL_0, b0, 0, 0);
    QH(a0h, b0, 2, 0);
    PHASE_END();

    // P2: reads b2(4) <- buf0
    RD_B2(0);
    PHASE_SYNC();
    QH(aL_0, b2, 0, 2);
    QH(a0h, b2, 2, 2);
    PHASE_END();

    // P3: reads a4(8) <- buf0; stage n0:B0,B1 -> buf0; vmcnt certifies o
    RD_A4(0);
    if (full) { STAGE(Bb, n0, 16384); STAGE(Bb1, n0, 24576); }
    PHASE_SYNC();
    QUAD4(a4, b0, 4, 0);
    __builtin_amdgcn_s_setprio(0);
    if (full) asm volatile("s_waitcnt vmcnt(4)" ::: "memory");
    else      asm volatile("s_waitcnt vmcnt(0)" ::: "memory");
    __builtin_amdgcn_s_barrier();

    // P4: reads aL_1(4) <- buf1 (certified); stage n0:A0 -> buf0
    RD_AL(65536, aL_1);
    if (full) STAGE(Ab, n0, 0);
    PHASE_SYNC();
    QUAD4(a4, b2, 4, 2);
    PHASE_END();

    // ====== K-step 2j+1 (buf1) ======
    // P5: reads a0h(4)+b0(4) <- buf1; stage n0:A1 -> buf0
    RD_A0H(65536);
    RD_B0(65536);
    if (full) STAGE(Ab1, n0, 8192);
    PHASE_SYNC();
    QH(aL_1, b0, 0, 0);
    QH(a0h, b0, 2, 0);
    PHASE_END();

    // P6: reads b2(4) <- buf1
    RD_B2(65536);
    PHASE_SYNC();
    QH(aL_1, b2, 0, 2);
    QH(a0h, b2, 2, 2);
    PHASE_END();

    // P7: reads a4(8) <- buf1; stage n1:B0,B1 -> buf1; vmcnt certifies n0
    RD_A4(65536);
    if (full) { STAGE(Bb, n1, 49152); STAGE(Bb1, n1, 57344); }
    PHASE_SYNC();
    QUAD4(a4, b0, 4, 0);
    __builtin_amdgcn_s_setprio(0);
    if (full) asm volatile("s_waitcnt vmcnt(4)" ::: "memory");
    else      asm volatile("s_waitcnt vmcnt(0)" ::: "memory");
    __builtin_amdgcn_s_barrier();

    // P8: reads aL_0(4) <- buf0 (step n0, certified); stage n1:A0 -> buf1
    if (full) {
      RD_AL(0, aL_0);
      STAGE(Ab, n1, 32768);
    }
    PHASE_SYNC();
    QUAD4(a4, b2, 4, 2);
    PHASE_END();
  }

  // epilogue: h as bf16 into the second half of each f32 output row slot.
  // C/D layout (16x16x32 bf16): col = lane&15, row = (lane>>4)*4 + r
  int crow0 = brow * BM + wm * 128;
  int ccol0 = bcol * BN + wn * 64;
  char* Cb = (char*)C;
#pragma unroll
  for (int mi = 0; mi < 8; ++mi)
#pragma unroll
    for (int ni = 0; ni < 4; ++ni) {
      int col = ccol0 + ni * 16 + lrow;
#pragma unroll
      for (int r = 0; r < 4; ++r) {
        int row = crow0 + mi * 16 + lkhi * 4 + r;
        *(__bf16*)(Cb + (size_t)row * 16384 + 8192 + col * 2) =
            (__bf16)acc[mi][ni][r];
      }
    }
}

// ---------- fused out_scale/bias + LayerNorm: bf16 h (2nd half-slot) -> f32 ----------
__global__ __launch_bounds__(256) void ln_fuse(
    float* __restrict__ out, const float* __restrict__ os,
    const float* __restrict__ bs, const float* __restrict__ g,
    const float* __restrict__ be) {
  constexpr int N = GN;  // 4096
  int row = blockIdx.x;
  const __bf16* hr = (const __bf16*)((const char*)out + (size_t)row * 16384 + 8192);
  float* orow = out + (size_t)row * N;
  int t = threadIdx.x;

  float v[16];
  float sum = 0.f, ssq = 0.f;
#pragma unroll
  for (int c = 0; c < 2; ++c) {
    int idx = c * 2048 + t * 8;       // 8 bf16 per chunk, 2 chunks/thread
    bf16x8 hv = *(const bf16x8*)(hr + idx);
    float4 s0 = *(const float4*)(os + idx);
    float4 s1 = *(const float4*)(os + idx + 4);
    float4 b0 = *(const float4*)(bs + idx);
    float4 b1 = *(const float4*)(bs + idx + 4);
#pragma unroll
    for (int j = 0; j < 4; ++j) {
      float a = (float)hv[j] * (&s0.x)[j] + (&b0.x)[j];
      v[c * 8 + j] = a;
      sum += a; ssq += a * a;
    }
#pragma unroll
    for (int j = 0; j < 4; ++j) {
      float a = (float)hv[4 + j] * (&s1.x)[j] + (&b1.x)[j];
      v[c * 8 + 4 + j] = a;
      sum += a; ssq += a * a;
    }
  }

  // wave64 reduce
#pragma unroll
  for (int off = 32; off > 0; off >>= 1) {
    sum += __shfl_down(sum, off);
    ssq += __shfl_down(ssq, off);
  }
  __shared__ float rs[8];
  int wid = t >> 6, lane = t & 63;
  if (lane == 0) { rs[wid] = sum; rs[4 + wid] = ssq; }
  __syncthreads();   // also separates all h reads from the in-place writes
  sum = rs[0] + rs[1] + rs[2] + rs[3];
  ssq = rs[4] + rs[5] + rs[6] + rs[7];

  float mean = sum * (1.f / N);
  float var = ssq * (1.f / N) - mean * mean;
  float rstd = rsqrtf(var + 1e-5f);

#pragma unroll
  for (int c = 0; c < 2; ++c) {
    int idx = c * 2048 + t * 8;
    float4 g0 = *(const float4*)(g + idx);
    float4 g1 = *(const float4*)(g + idx + 4);
    float4 e0 = *(const float4*)(be + idx);
    float4 e1 = *(const float4*)(be + idx + 4);
    float4 o0, o1;
#pragma unroll
    for (int j = 0; j < 4; ++j) {
      (&o0.x)[j] = (v[c * 8 + j] - mean) * rstd * (&g0.x)[j] + (&e0.x)[j];
      (&o1.x)[j] = (v[c * 8 + 4 + j] - mean) * rstd * (&g1.x)[j] + (&e1.x)[j];
    }
    *(float4*)(orow + idx) = o0;
    *(float4*)(orow + idx + 4) = o1;
  }
}

extern "C" void kernel_launch(void* const* d_in, const int* in_sizes, int n_in,
                              void* d_out, int out_size, void* d_ws, size_t ws_size,
                              hipStream_t stream) {
  const float* x      = (const float*)d_in[0];  // [4,2048,4096]
  const float* w      = (const float*)d_in[1];  // [4096,4096]
  const float* iscale = (const float*)d_in[2];  // [4096]
  const float* oscale = (const float*)d_in[3];  // [4096]
  const float* bias   = (const float*)d_in[4];  // [4096]
  const float* gamma  = (const float*)d_in[5];  // [4096]
  const float* beta   = (const float*)d_in[6];  // [4096]
  float* out = (float*)d_out;                   // [8192,4096] f32

  __bf16* Abf = (__bf16*)d_ws;                                   // 67 MB
  __bf16* Wbf = (__bf16*)((char*)d_ws + (size_t)GM * GK * 2);    // 33.5 MB

  (void)hipFuncSetAttribute((const void*)gemm_bt,
                            hipFuncAttributeMaxDynamicSharedMemorySize, LDS_BYTES);

  prep_fused<<<PX_BLOCKS + PW_BLOCKS, 256, 0, stream>>>(x, iscale, w, Abf, Wbf);
  gemm_bt<<<(GM / BM) * (GN / BN), 512, LDS_BYTES, stream>>>(Abf, Wbf, out);
  ln_fuse<<<GM, 256, 0, stream>>>(out, oscale, bias, gamma, beta);
}

// Round 17
// 219.704 us; speedup vs baseline: 1.4084x; 1.3358x over previous
//
#include <hip/hip_runtime.h>
#include <hip/hip_bf16.h>

// Problem constants (fixed by reference): B=4, S=2048, DIN=DOUT=4096
constexpr int GM = 8192;   // B*S rows
constexpr int GN = 4096;   // DOUT
constexpr int GK = 4096;   // DIN

constexpr int BM = 256, BN = 256, BK = 64;    // BK in i8 elements (= bytes)
constexpr int NSTEP = GK / BK;                // 64 K-steps
constexpr int SLOT_BYTES = (BM + BN) * BK;    // 32768 (A 16K + B 16K, i8)
constexpr int LDS_BYTES = 3 * SLOT_BYTES;     // 98304 = 96 KiB, 3-slot ring

using bf16x8 = __attribute__((ext_vector_type(8))) __bf16;
using i32x4  = __attribute__((ext_vector_type(4))) int;

// -------- prep_x: per-row absmax quantize  A_i8 = rint(x*s*127/rowmax) --------
// One block per row. alpha[row] = rowmax/127 so h = alpha * (i32 acc) exactly
// reconstructs x̂·sgn(W) up to the ±0.5 LSB rounding (i32 accumulation exact).
__global__ __launch_bounds__(256) void prep_x_i8(
    const float* __restrict__ x, const float* __restrict__ iscale,
    signed char* __restrict__ A, float* __restrict__ alpha) {
  int row = blockIdx.x;
  const float* xr = x + (size_t)row * GK;
  int t = threadIdx.x;

  float v[16];
  float mx = 0.f;
#pragma unroll
  for (int p = 0; p < 4; ++p) {
    int idx = p * 1024 + t * 4;
    float4 xv = *(const float4*)(xr + idx);
    float4 sv = *(const float4*)(iscale + idx);
    float a0 = xv.x * sv.x, a1 = xv.y * sv.y, a2 = xv.z * sv.z, a3 = xv.w * sv.w;
    v[p * 4 + 0] = a0; v[p * 4 + 1] = a1; v[p * 4 + 2] = a2; v[p * 4 + 3] = a3;
    mx = fmaxf(mx, fmaxf(fmaxf(fabsf(a0), fabsf(a1)), fmaxf(fabsf(a2), fabsf(a3))));
  }
#pragma unroll
  for (int off = 32; off > 0; off >>= 1)
    mx = fmaxf(mx, __shfl_down(mx, off));
  __shared__ float rm[4];
  int wid = t >> 6, lane = t & 63;
  if (lane == 0) rm[wid] = mx;
  __syncthreads();
  float m = fmaxf(fmaxf(rm[0], rm[1]), fmaxf(rm[2], rm[3]));
  float inv = m > 0.f ? 127.f / m : 0.f;
  if (t == 0) alpha[row] = m * (1.f / 127.f);

#pragma unroll
  for (int p = 0; p < 4; ++p) {
    int idx = p * 1024 + t * 4;
    char4 q;
    int q0 = (int)rintf(v[p * 4 + 0] * inv);
    int q1 = (int)rintf(v[p * 4 + 1] * inv);
    int q2 = (int)rintf(v[p * 4 + 2] * inv);
    int q3 = (int)rintf(v[p * 4 + 3] * inv);
    q.x = (signed char)max(-127, min(127, q0));
    q.y = (signed char)max(-127, min(127, q1));
    q.z = (signed char)max(-127, min(127, q2));
    q.w = (signed char)max(-127, min(127, q3));
    *(char4*)(A + (size_t)row * GK + idx) = q;
  }
}

// -------------------- prep_w: W_i8 = sign(w) in {-1,0,+1} (exact) --------------------
__global__ __launch_bounds__(256) void prep_w_i8(
    const float* __restrict__ w, signed char* __restrict__ Wb) {
  int e = (blockIdx.x * 256 + threadIdx.x) * 8;
  float4 v0 = *(const float4*)(w + e);
  float4 v1 = *(const float4*)(w + e + 4);
  auto sg = [](float v) -> signed char {
    return (signed char)((v > 0.f) - (v < 0.f));
  };
  union { signed char c[8]; unsigned long long u; } o;
  o.c[0] = sg(v0.x); o.c[1] = sg(v0.y); o.c[2] = sg(v0.z); o.c[3] = sg(v0.w);
  o.c[4] = sg(v1.x); o.c[5] = sg(v1.y); o.c[6] = sg(v1.z); o.c[7] = sg(v1.w);
  *(unsigned long long*)(Wb + e) = o.u;
}

// -------------------- GEMM (i8): C[m][n] = alpha_m * sum_k qA[m][k]*sgnW[n][k] ----
// i8 halves BOTH measured binders vs the bf16 family (R5-R16 flat at ~51%
// MfmaUtil, MFMA-pipe 2484 + LDS-pipe 2304 cyc/K-step alternating):
// mfma_i32_16x16x64_i8 at 2x rate (MFMA-min 1242 cyc), fragments 16B/lane ->
// 12 b128 reads/wave/K-step (LDS ~1150 cyc), staging 32 KB/K-step, and
// 2 phases/K-step -> 4 barriers (vs 8).
// Structure: 256x256 tile, 512 threads (2M x 4N waves, wave tile 128x64 =
// 8mi x 4ni frags), 3-slot LDS ring (96 KiB), stage-2-ahead:
//   Ph1: read a0-3(4)+b0-3(4); STAGE_A(t+2); bar; lgkm0; 16 MFMA; bar
//   Ph2: read a4-7(4); STAGE_B(t+2); bar; lgkm0; 16 MFMA; vmcnt(4); bar
// vmcnt(4) at step end: outstanding = (t+1)'s 4 + (t+2)'s 4 -> retires
// exactly step t+1 before it is read. Ring WAR (R3-proven): slot (t+2)%3
// was last read at step t-1, reads drained (lgkm0) before that step's
// end barrier, stage follows it.
// Swizzle (R3/R11-verified 0-conflict at this exact 64-B-row geometry):
// 16-B chunk c of row r holds k-group c^((r>>1)&3); stage pre-permutes the
// global source chunk, reads XOR the chunk index. i8 16x16x64 fragment:
// row/col = l&15, k = (l>>4)*16 + e (one 16-B chunk per lane); C/D layout
// dtype-independent: col = lane&15, row = (lane>>4)*4 + r [m121-m128].
// Epilogue: h = alpha[row]*acc -> bf16 into 2nd half of each f32 row slot.
__device__ inline void gload16(const void* g, const void* l) {
  __builtin_amdgcn_global_load_lds(
      (const __attribute__((address_space(1))) void*)g,
      (__attribute__((address_space(3))) void*)l, 16, 0, 0);
}

__global__ __launch_bounds__(512, 2) void gemm_i8(
    const signed char* __restrict__ A, const signed char* __restrict__ Bm,
    const float* __restrict__ alpha, float* __restrict__ C) {
  extern __shared__ signed char lds8[];  // 3 slots x (A 16K + B 16K)

  // Square XCD chunking (FETCH ~197 MB on the bf16 path; halves here)
  int bid = blockIdx.x;            // 0..511
  int x = bid & 7, idx = bid >> 3;
  int brow = ((x & 3) << 3) | (idx & 7);   // 0..31
  int bcol = ((x >> 2) << 3) | (idx >> 3); // 0..15

  int tid = threadIdx.x, wid = tid >> 6, lane = tid & 63;
  int wm = wid & 1, wn = wid >> 1;         // 2M x 4N waves
  int lrow = lane & 15, lkhi = lane >> 4;

  const signed char* Ab = A + (size_t)(brow * BM) * GK;
  const signed char* Bb = Bm + (size_t)(bcol * BN) * GK;

  // read-side swizzled chunk (4 x 16-B chunks per 64-B row)
  int rchunk = lkhi ^ ((lrow >> 1) & 3);
  int avbase = (wm * 128 + lrow) * 64 + rchunk * 16;          // + mi*1024
  int bvbase = 16384 + (wn * 64 + lrow) * 64 + rchunk * 16;   // + ni*1024

  // stage-side: thread t covers row t>>2 (0..127), chunk t&3; source chunk
  // pre-permuted so LDS chunk c of row r holds k-group c^((r>>1)&3).
  // Row+128 (2nd issue) preserves (r>>1)&3, so the same gcol applies.
  int grow = tid >> 2;
  int gcol = ((tid & 3) ^ ((tid >> 3) & 3)) * 16;  // byte offset in 64-B window

  auto STAGE_A = [&](int kstep, int si) {
    const signed char* s = Ab + (size_t)grow * GK + kstep * BK + gcol;
    const signed char* d = lds8 + si * SLOT_BYTES + tid * 16;
    gload16(s, d);
    gload16(s + (size_t)128 * GK, d + 8192);
  };
  auto STAGE_B = [&](int kstep, int si) {
    const signed char* s = Bb + (size_t)grow * GK + kstep * BK + gcol;
    const signed char* d = lds8 + si * SLOT_BYTES + 16384 + tid * 16;
    gload16(s, d);
    gload16(s + (size_t)128 * GK, d + 8192);
  };

  i32x4 acc[8][4] = {};

  // prologue: steps 0,1 staged; vmcnt(4) retires step 0 (step 1 in flight)
  STAGE_A(0, 0); STAGE_B(0, 0);
  STAGE_A(1, 1); STAGE_B(1, 1);
  asm volatile("s_waitcnt vmcnt(4)" ::: "memory");
  __builtin_amdgcn_s_barrier();

  int rc = 0, rs = 2;
  for (int t = 0; t < NSTEP; ++t) {
    const signed char* sl = lds8 + rc * SLOT_BYTES;
    i32x4 af[8], bf[4];

    // ---- Ph1: reads a0-3 + b0-3 (8 b128); stage A(t+2); 16 MFMA (mi 0-3)
#pragma unroll
    for (int mi = 0; mi < 4; ++mi)
      af[mi] = *(const i32x4*)(sl + avbase + mi * 1024);
#pragma unroll
    for (int ni = 0; ni < 4; ++ni)
      bf[ni] = *(const i32x4*)(sl + bvbase + ni * 1024);
    if (t + 2 < NSTEP) STAGE_A(t + 2, rs);
    __builtin_amdgcn_s_barrier();
    asm volatile("s_waitcnt lgkmcnt(0)" ::: "memory");
    __builtin_amdgcn_sched_barrier(0);
    __builtin_amdgcn_s_setprio(1);
#pragma unroll
    for (int mi = 0; mi < 4; ++mi)
#pragma unroll
      for (int ni = 0; ni < 4; ++ni)
        acc[mi][ni] = __builtin_amdgcn_mfma_i32_16x16x64_i8(
            af[mi], bf[ni], acc[mi][ni], 0, 0, 0);
    __builtin_amdgcn_s_setprio(0);
    __builtin_amdgcn_s_barrier();

    // ---- Ph2: reads a4-7 (4 b128); stage B(t+2); 16 MFMA (mi 4-7); vmcnt(4)
#pragma unroll
    for (int mi = 0; mi < 4; ++mi)
      af[4 + mi] = *(const i32x4*)(sl + avbase + (4 + mi) * 1024);
    if (t + 2 < NSTEP) STAGE_B(t + 2, rs);
    __builtin_amdgcn_s_barrier();
    asm volatile("s_waitcnt lgkmcnt(0)" ::: "memory");
    __builtin_amdgcn_sched_barrier(0);
    __builtin_amdgcn_s_setprio(1);
#pragma unroll
    for (int mi = 0; mi < 4; ++mi)
#pragma unroll
      for (int ni = 0; ni < 4; ++ni)
        acc[4 + mi][ni] = __builtin_amdgcn_mfma_i32_16x16x64_i8(
            af[4 + mi], bf[ni], acc[4 + mi][ni], 0, 0, 0);
    __builtin_amdgcn_s_setprio(0);
    __builtin_amdgcn_sched_barrier(0);
    if (t + 2 < NSTEP) asm volatile("s_waitcnt vmcnt(4)" ::: "memory");
    else               asm volatile("s_waitcnt vmcnt(0)" ::: "memory");
    __builtin_amdgcn_s_barrier();
    rc = (rc == 2) ? 0 : rc + 1;
    rs = (rs == 2) ? 0 : rs + 1;
  }

  // epilogue: h = alpha[row]*acc as bf16 into 2nd half of each f32 row slot.
  // C/D layout: col = lane&15, row = (lane>>4)*4 + r
  int crow0 = brow * BM + wm * 128;
  int ccol0 = bcol * BN + wn * 64;
  char* Cb = (char*)C;
#pragma unroll
  for (int mi = 0; mi < 8; ++mi)
#pragma unroll
    for (int ni = 0; ni < 4; ++ni) {
      int col = ccol0 + ni * 16 + lrow;
#pragma unroll
      for (int r = 0; r < 4; ++r) {
        int row = crow0 + mi * 16 + lkhi * 4 + r;
        float h = alpha[row] * (float)acc[mi][ni][r];
        *(__bf16*)(Cb + (size_t)row * 16384 + 8192 + col * 2) = (__bf16)h;
      }
    }
}

// ---------- fused out_scale/bias + LayerNorm: bf16 h (2nd half-slot) -> f32 ----------
__global__ __launch_bounds__(256) void ln_fuse(
    float* __restrict__ out, const float* __restrict__ os,
    const float* __restrict__ bs, const float* __restrict__ g,
    const float* __restrict__ be) {
  constexpr int N = GN;  // 4096
  int row = blockIdx.x;
  const __bf16* hr = (const __bf16*)((const char*)out + (size_t)row * 16384 + 8192);
  float* orow = out + (size_t)row * N;
  int t = threadIdx.x;

  float v[16];
  float sum = 0.f, ssq = 0.f;
#pragma unroll
  for (int c = 0; c < 2; ++c) {
    int idx = c * 2048 + t * 8;       // 8 bf16 per chunk, 2 chunks/thread
    bf16x8 hv = *(const bf16x8*)(hr + idx);
    float4 s0 = *(const float4*)(os + idx);
    float4 s1 = *(const float4*)(os + idx + 4);
    float4 b0 = *(const float4*)(bs + idx);
    float4 b1 = *(const float4*)(bs + idx + 4);
#pragma unroll
    for (int j = 0; j < 4; ++j) {
      float a = (float)hv[j] * (&s0.x)[j] + (&b0.x)[j];
      v[c * 8 + j] = a;
      sum += a; ssq += a * a;
    }
#pragma unroll
    for (int j = 0; j < 4; ++j) {
      float a = (float)hv[4 + j] * (&s1.x)[j] + (&b1.x)[j];
      v[c * 8 + 4 + j] = a;
      sum += a; ssq += a * a;
    }
  }

  // wave64 reduce
#pragma unroll
  for (int off = 32; off > 0; off >>= 1) {
    sum += __shfl_down(sum, off);
    ssq += __shfl_down(ssq, off);
  }
  __shared__ float rs[8];
  int wid = t >> 6, lane = t & 63;
  if (lane == 0) { rs[wid] = sum; rs[4 + wid] = ssq; }
  __syncthreads();   // also separates all h reads from the in-place writes
  sum = rs[0] + rs[1] + rs[2] + rs[3];
  ssq = rs[4] + rs[5] + rs[6] + rs[7];

  float mean = sum * (1.f / N);
  float var = ssq * (1.f / N) - mean * mean;
  float rstd = rsqrtf(var + 1e-5f);

#pragma unroll
  for (int c = 0; c < 2; ++c) {
    int idx = c * 2048 + t * 8;
    float4 g0 = *(const float4*)(g + idx);
    float4 g1 = *(const float4*)(g + idx + 4);
    float4 e0 = *(const float4*)(be + idx);
    float4 e1 = *(const float4*)(be + idx + 4);
    float4 o0, o1;
#pragma unroll
    for (int j = 0; j < 4; ++j) {
      (&o0.x)[j] = (v[c * 8 + j] - mean) * rstd * (&g0.x)[j] + (&e0.x)[j];
      (&o1.x)[j] = (v[c * 8 + 4 + j] - mean) * rstd * (&g1.x)[j] + (&e1.x)[j];
    }
    *(float4*)(orow + idx) = o0;
    *(float4*)(orow + idx + 4) = o1;
  }
}

extern "C" void kernel_launch(void* const* d_in, const int* in_sizes, int n_in,
                              void* d_out, int out_size, void* d_ws, size_t ws_size,
                              hipStream_t stream) {
  const float* x      = (const float*)d_in[0];  // [4,2048,4096]
  const float* w      = (const float*)d_in[1];  // [4096,4096]
  const float* iscale = (const float*)d_in[2];  // [4096]
  const float* oscale = (const float*)d_in[3];  // [4096]
  const float* bias   = (const float*)d_in[4];  // [4096]
  const float* gamma  = (const float*)d_in[5];  // [4096]
  const float* beta   = (const float*)d_in[6];  // [4096]
  float* out = (float*)d_out;                   // [8192,4096] f32

  signed char* Ai8 = (signed char*)d_ws;                         // 33.6 MB
  signed char* Wi8 = (signed char*)d_ws + (size_t)GM * GK;       // 16.8 MB
  float* alpha = (float*)((char*)d_ws + (size_t)GM * GK + (size_t)GN * GK);  // 32 KB

  (void)hipFuncSetAttribute((const void*)gemm_i8,
                            hipFuncAttributeMaxDynamicSharedMemorySize, LDS_BYTES);

  prep_x_i8<<<GM, 256, 0, stream>>>(x, iscale, Ai8, alpha);
  prep_w_i8<<<(GN * GK) / (256 * 8), 256, 0, stream>>>(w, Wi8);
  gemm_i8<<<(GM / BM) * (GN / BN), 512, LDS_BYTES, stream>>>(Ai8, Wi8, alpha, out);
  ln_fuse<<<GM, 256, 0, stream>>>(out, oscale, bias, gamma, beta);
}

// Round 18
// 217.912 us; speedup vs baseline: 1.4200x; 1.0082x over previous
//
#include <hip/hip_runtime.h>
#include <hip/hip_bf16.h>

// Problem constants (fixed by reference): B=4, S=2048, DIN=DOUT=4096
constexpr int GM = 8192;   // B*S rows
constexpr int GN = 4096;   // DOUT
constexpr int GK = 4096;   // DIN

constexpr int BM = 256, BN = 256, BK = 64;    // BK in i8 elements (= bytes)
constexpr int NSTEP = GK / BK;                // 64 K-steps
constexpr int SLOT_BYTES = (BM + BN) * BK;    // 32768 (A 16K + B 16K, i8)
constexpr int LDS_BYTES = 2 * SLOT_BYTES;     // 65536 -> 2 blocks/CU

constexpr int PX_BLOCKS = GM;                          // 8192 (1 block/row)
constexpr int PW_BLOCKS = (GN * GK) / (256 * 8);       // 8192

using bf16x8 = __attribute__((ext_vector_type(8))) __bf16;
using i32x4  = __attribute__((ext_vector_type(4))) int;

// ---- fused prep: rows -> per-row absmax i8 quantize; tail -> sign(w) i8 ----
__global__ __launch_bounds__(256) void prep_fused_i8(
    const float* __restrict__ x, const float* __restrict__ iscale,
    const float* __restrict__ w, signed char* __restrict__ A,
    signed char* __restrict__ Wb, float* __restrict__ alpha) {
  int b = blockIdx.x;
  int t = threadIdx.x;
  if (b < PX_BLOCKS) {
    // prep_x: one block per row; alpha[row] = rowmax/127; A = rint(x*s/alpha)
    int row = b;
    const float* xr = x + (size_t)row * GK;
    float v[16];
    float mx = 0.f;
#pragma unroll
    for (int p = 0; p < 4; ++p) {
      int idx = p * 1024 + t * 4;
      float4 xv = *(const float4*)(xr + idx);
      float4 sv = *(const float4*)(iscale + idx);
      float a0 = xv.x * sv.x, a1 = xv.y * sv.y, a2 = xv.z * sv.z, a3 = xv.w * sv.w;
      v[p * 4 + 0] = a0; v[p * 4 + 1] = a1; v[p * 4 + 2] = a2; v[p * 4 + 3] = a3;
      mx = fmaxf(mx, fmaxf(fmaxf(fabsf(a0), fabsf(a1)), fmaxf(fabsf(a2), fabsf(a3))));
    }
#pragma unroll
    for (int off = 32; off > 0; off >>= 1)
      mx = fmaxf(mx, __shfl_down(mx, off));
    __shared__ float rm[4];
    int wid = t >> 6, lane = t & 63;
    if (lane == 0) rm[wid] = mx;
    __syncthreads();
    float m = fmaxf(fmaxf(rm[0], rm[1]), fmaxf(rm[2], rm[3]));
    float inv = m > 0.f ? 127.f / m : 0.f;
    if (t == 0) alpha[row] = m * (1.f / 127.f);
#pragma unroll
    for (int p = 0; p < 4; ++p) {
      int idx = p * 1024 + t * 4;
      char4 q;
      int q0 = (int)rintf(v[p * 4 + 0] * inv);
      int q1 = (int)rintf(v[p * 4 + 1] * inv);
      int q2 = (int)rintf(v[p * 4 + 2] * inv);
      int q3 = (int)rintf(v[p * 4 + 3] * inv);
      q.x = (signed char)max(-127, min(127, q0));
      q.y = (signed char)max(-127, min(127, q1));
      q.z = (signed char)max(-127, min(127, q2));
      q.w = (signed char)max(-127, min(127, q3));
      *(char4*)(A + (size_t)row * GK + idx) = q;
    }
  } else {
    // prep_w: sign(w) in {-1,0,+1}, exact
    int e = ((b - PX_BLOCKS) * 256 + t) * 8;
    float4 v0 = *(const float4*)(w + e);
    float4 v1 = *(const float4*)(w + e + 4);
    auto sg = [](float v) -> signed char {
      return (signed char)((v > 0.f) - (v < 0.f));
    };
    union { signed char c[8]; unsigned long long u; } o;
    o.c[0] = sg(v0.x); o.c[1] = sg(v0.y); o.c[2] = sg(v0.z); o.c[3] = sg(v0.w);
    o.c[4] = sg(v1.x); o.c[5] = sg(v1.y); o.c[6] = sg(v1.z); o.c[7] = sg(v1.w);
    *(unsigned long long*)(Wb + e) = o.u;
  }
}

// -------------------- GEMM (i8): C[m][n] = alpha_m * sum_k qA[m][k]*sgnW[n][k] ----
// R17 structure with a 2-SLOT ring (64 KiB LDS) -> TWO blocks co-resident
// per CU (the lever the bf16 family never had: its 96-128 KiB LDS forced
// 1 block/CU, so the MFMA-pipe and LDS-pipe strictly alternated; R17's
// per-K-step accounting: measured 2728 cyc = MFMA 1307 + LDS ~1450).
// With 2 independent blocks, one block's barrier/lgkm drains overlap the
// other block's MFMA (m114). Stage-1-ahead: both halves of step t+1 are
// issued at the top of step t into the other slot; end-of-step vmcnt(0)
// has a full K-step (~2700 cyc >> 900 cyc HBM) of cover, and the partner
// block hides the residual. WAR: the staged slot's reads (step t-1)
// drained via lgkm0 before t-1's end barrier, which precedes the stage.
// Swizzle (R3/R11/R17-verified 0-conflict, 64-B rows): 16-B chunk c of
// row r holds k-group c^((r>>1)&3); stage pre-permutes the global source
// chunk, reads XOR the chunk index. i8 16x16x64 fragment: row/col = l&15,
// k = (l>>4)*16 + e; C/D layout: col = lane&15, row = (lane>>4)*4 + r.
// Epilogue: h = alpha[row]*acc -> bf16 into 2nd half of each f32 row slot.
__device__ inline void gload16(const void* g, const void* l) {
  __builtin_amdgcn_global_load_lds(
      (const __attribute__((address_space(1))) void*)g,
      (__attribute__((address_space(3))) void*)l, 16, 0, 0);
}

__global__ __launch_bounds__(512, 2) void gemm_i8(
    const signed char* __restrict__ A, const signed char* __restrict__ Bm,
    const float* __restrict__ alpha, float* __restrict__ C) {
  extern __shared__ signed char lds8[];  // 2 slots x (A 16K + B 16K)

  // Square XCD chunking (R3-R17)
  int bid = blockIdx.x;            // 0..511
  int x = bid & 7, idx = bid >> 3;
  int brow = ((x & 3) << 3) | (idx & 7);   // 0..31
  int bcol = ((x >> 2) << 3) | (idx >> 3); // 0..15

  int tid = threadIdx.x, wid = tid >> 6, lane = tid & 63;
  int wm = wid & 1, wn = wid >> 1;         // 2M x 4N waves
  int lrow = lane & 15, lkhi = lane >> 4;

  const signed char* Ab = A + (size_t)(brow * BM) * GK;
  const signed char* Bb = Bm + (size_t)(bcol * BN) * GK;

  // read-side swizzled chunk (4 x 16-B chunks per 64-B row)
  int rchunk = lkhi ^ ((lrow >> 1) & 3);
  int avbase = (wm * 128 + lrow) * 64 + rchunk * 16;          // + mi*1024
  int bvbase = 16384 + (wn * 64 + lrow) * 64 + rchunk * 16;   // + ni*1024

  // stage-side: thread t covers row t>>2 (0..127), chunk t&3; source chunk
  // pre-permuted so LDS chunk c of row r holds k-group c^((r>>1)&3).
  // Row+128 (2nd issue) preserves (r>>1)&3, so the same gcol applies.
  int grow = tid >> 2;
  int gcol = ((tid & 3) ^ ((tid >> 3) & 3)) * 16;  // byte offset in 64-B window

  auto STAGE = [&](int kstep, int si) {
    const signed char* sA = Ab + (size_t)grow * GK + kstep * BK + gcol;
    const signed char* dA = lds8 + si * SLOT_BYTES + tid * 16;
    gload16(sA, dA);
    gload16(sA + (size_t)128 * GK, dA + 8192);
    const signed char* sB = Bb + (size_t)grow * GK + kstep * BK + gcol;
    gload16(sB, dA + 16384);
    gload16(sB + (size_t)128 * GK, dA + 16384 + 8192);
  };

  i32x4 acc[8][4] = {};

  // prologue: step 0 -> slot 0; full drain (distance irrelevant once)
  STAGE(0, 0);
  asm volatile("s_waitcnt vmcnt(0)" ::: "memory");
  __builtin_amdgcn_s_barrier();

  for (int t = 0; t < NSTEP; ++t) {
    const signed char* sl = lds8 + (t & 1) * SLOT_BYTES;
    if (t + 1 < NSTEP) STAGE(t + 1, (t + 1) & 1);

    i32x4 af[8], bf[4];
    // ---- Ph1: reads a0-3 + b0-3 (8 b128); 16 MFMA (mi 0-3)
#pragma unroll
    for (int mi = 0; mi < 4; ++mi)
      af[mi] = *(const i32x4*)(sl + avbase + mi * 1024);
#pragma unroll
    for (int ni = 0; ni < 4; ++ni)
      bf[ni] = *(const i32x4*)(sl + bvbase + ni * 1024);
    __builtin_amdgcn_s_barrier();
    asm volatile("s_waitcnt lgkmcnt(0)" ::: "memory");
    __builtin_amdgcn_sched_barrier(0);
    __builtin_amdgcn_s_setprio(1);
#pragma unroll
    for (int mi = 0; mi < 4; ++mi)
#pragma unroll
      for (int ni = 0; ni < 4; ++ni)
        acc[mi][ni] = __builtin_amdgcn_mfma_i32_16x16x64_i8(
            af[mi], bf[ni], acc[mi][ni], 0, 0, 0);
    __builtin_amdgcn_s_setprio(0);
    __builtin_amdgcn_s_barrier();

    // ---- Ph2: reads a4-7 (4 b128); 16 MFMA (mi 4-7)
#pragma unroll
    for (int mi = 0; mi < 4; ++mi)
      af[4 + mi] = *(const i32x4*)(sl + avbase + (4 + mi) * 1024);
    __builtin_amdgcn_s_barrier();
    asm volatile("s_waitcnt lgkmcnt(0)" ::: "memory");
    __builtin_amdgcn_sched_barrier(0);
    __builtin_amdgcn_s_setprio(1);
#pragma unroll
    for (int mi = 0; mi < 4; ++mi)
#pragma unroll
      for (int ni = 0; ni < 4; ++ni)
        acc[4 + mi][ni] = __builtin_amdgcn_mfma_i32_16x16x64_i8(
            af[4 + mi], bf[ni], acc[4 + mi][ni], 0, 0, 0);
    __builtin_amdgcn_s_setprio(0);

    // ---- step boundary: ensure step t+1 landed (issued a full K-step ago)
    if (t + 1 < NSTEP) {
      __builtin_amdgcn_sched_barrier(0);
      asm volatile("s_waitcnt vmcnt(0)" ::: "memory");
      __builtin_amdgcn_s_barrier();
    }
  }

  // epilogue: h = alpha[row]*acc as bf16 into 2nd half of each f32 row slot.
  // C/D layout: col = lane&15, row = (lane>>4)*4 + r
  int crow0 = brow * BM + wm * 128;
  int ccol0 = bcol * BN + wn * 64;
  char* Cb = (char*)C;
#pragma unroll
  for (int mi = 0; mi < 8; ++mi)
#pragma unroll
    for (int ni = 0; ni < 4; ++ni) {
      int col = ccol0 + ni * 16 + lrow;
#pragma unroll
      for (int r = 0; r < 4; ++r) {
        int row = crow0 + mi * 16 + lkhi * 4 + r;
        float h = alpha[row] * (float)acc[mi][ni][r];
        *(__bf16*)(Cb + (size_t)row * 16384 + 8192 + col * 2) = (__bf16)h;
      }
    }
}

// ---------- fused out_scale/bias + LayerNorm: bf16 h (2nd half-slot) -> f32 ----------
__global__ __launch_bounds__(256) void ln_fuse(
    float* __restrict__ out, const float* __restrict__ os,
    const float* __restrict__ bs, const float* __restrict__ g,
    const float* __restrict__ be) {
  constexpr int N = GN;  // 4096
  int row = blockIdx.x;
  const __bf16* hr = (const __bf16*)((const char*)out + (size_t)row * 16384 + 8192);
  float* orow = out + (size_t)row * N;
  int t = threadIdx.x;

  float v[16];
  float sum = 0.f, ssq = 0.f;
#pragma unroll
  for (int c = 0; c < 2; ++c) {
    int idx = c * 2048 + t * 8;       // 8 bf16 per chunk, 2 chunks/thread
    bf16x8 hv = *(const bf16x8*)(hr + idx);
    float4 s0 = *(const float4*)(os + idx);
    float4 s1 = *(const float4*)(os + idx + 4);
    float4 b0 = *(const float4*)(bs + idx);
    float4 b1 = *(const float4*)(bs + idx + 4);
#pragma unroll
    for (int j = 0; j < 4; ++j) {
      float a = (float)hv[j] * (&s0.x)[j] + (&b0.x)[j];
      v[c * 8 + j] = a;
      sum += a; ssq += a * a;
    }
#pragma unroll
    for (int j = 0; j < 4; ++j) {
      float a = (float)hv[4 + j] * (&s1.x)[j] + (&b1.x)[j];
      v[c * 8 + 4 + j] = a;
      sum += a; ssq += a * a;
    }
  }

  // wave64 reduce
#pragma unroll
  for (int off = 32; off > 0; off >>= 1) {
    sum += __shfl_down(sum, off);
    ssq += __shfl_down(ssq, off);
  }
  __shared__ float rs[8];
  int wid = t >> 6, lane = t & 63;
  if (lane == 0) { rs[wid] = sum; rs[4 + wid] = ssq; }
  __syncthreads();   // also separates all h reads from the in-place writes
  sum = rs[0] + rs[1] + rs[2] + rs[3];
  ssq = rs[4] + rs[5] + rs[6] + rs[7];

  float mean = sum * (1.f / N);
  float var = ssq * (1.f / N) - mean * mean;
  float rstd = rsqrtf(var + 1e-5f);

#pragma unroll
  for (int c = 0; c < 2; ++c) {
    int idx = c * 2048 + t * 8;
    float4 g0 = *(const float4*)(g + idx);
    float4 g1 = *(const float4*)(g + idx + 4);
    float4 e0 = *(const float4*)(be + idx);
    float4 e1 = *(const float4*)(be + idx + 4);
    float4 o0, o1;
#pragma unroll
    for (int j = 0; j < 4; ++j) {
      (&o0.x)[j] = (v[c * 8 + j] - mean) * rstd * (&g0.x)[j] + (&e0.x)[j];
      (&o1.x)[j] = (v[c * 8 + 4 + j] - mean) * rstd * (&g1.x)[j] + (&e1.x)[j];
    }
    *(float4*)(orow + idx) = o0;
    *(float4*)(orow + idx + 4) = o1;
  }
}

extern "C" void kernel_launch(void* const* d_in, const int* in_sizes, int n_in,
                              void* d_out, int out_size, void* d_ws, size_t ws_size,
                              hipStream_t stream) {
  const float* x      = (const float*)d_in[0];  // [4,2048,4096]
  const float* w      = (const float*)d_in[1];  // [4096,4096]
  const float* iscale = (const float*)d_in[2];  // [4096]
  const float* oscale = (const float*)d_in[3];  // [4096]
  const float* bias   = (const float*)d_in[4];  // [4096]
  const float* gamma  = (const float*)d_in[5];  // [4096]
  const float* beta   = (const float*)d_in[6];  // [4096]
  float* out = (float*)d_out;                   // [8192,4096] f32

  signed char* Ai8 = (signed char*)d_ws;                         // 33.6 MB
  signed char* Wi8 = (signed char*)d_ws + (size_t)GM * GK;       // 16.8 MB
  float* alpha = (float*)((char*)d_ws + (size_t)GM * GK + (size_t)GN * GK);  // 32 KB

  (void)hipFuncSetAttribute((const void*)gemm_i8,
                            hipFuncAttributeMaxDynamicSharedMemorySize, LDS_BYTES);

  prep_fused_i8<<<PX_BLOCKS + PW_BLOCKS, 256, 0, stream>>>(x, iscale, w, Ai8,
                                                           Wi8, alpha);
  gemm_i8<<<(GM / BM) * (GN / BN), 512, LDS_BYTES, stream>>>(Ai8, Wi8, alpha, out);
  ln_fuse<<<GM, 256, 0, stream>>>(out, oscale, bias, gamma, beta);
}

// Round 19
// 213.190 us; speedup vs baseline: 1.4515x; 1.0221x over previous
//
#include <hip/hip_runtime.h>
#include <hip/hip_bf16.h>

// Problem constants (fixed by reference): B=4, S=2048, DIN=DOUT=4096
constexpr int GM = 8192;   // B*S rows
constexpr int GN = 4096;   // DOUT
constexpr int GK = 4096;   // DIN

constexpr int BM = 256, BN = 256, BK = 64;    // BK in i8 elements (= bytes)
constexpr int NSTEP = GK / BK;                // 64 K-steps
constexpr int SLOT_BYTES = (BM + BN) * BK;    // 32768 (A 16K + B 16K, i8)
constexpr int LDS_BYTES = 2 * SLOT_BYTES;     // 65536

constexpr int PX_BLOCKS = GM;                          // 8192 (1 block/row)
constexpr int PW_BLOCKS = (GN * GK) / (256 * 8);       // 8192

using bf16x8 = __attribute__((ext_vector_type(8))) __bf16;
using i32x4  = __attribute__((ext_vector_type(4))) int;

// ---- fused prep: rows -> per-row absmax i8 quantize; tail -> sign(w) i8 ----
__global__ __launch_bounds__(256) void prep_fused_i8(
    const float* __restrict__ x, const float* __restrict__ iscale,
    const float* __restrict__ w, signed char* __restrict__ A,
    signed char* __restrict__ Wb, float* __restrict__ alpha) {
  int b = blockIdx.x;
  int t = threadIdx.x;
  if (b < PX_BLOCKS) {
    // prep_x: one block per row; alpha[row] = rowmax/127; A = rint(x*s/alpha)
    int row = b;
    const float* xr = x + (size_t)row * GK;
    float v[16];
    float mx = 0.f;
#pragma unroll
    for (int p = 0; p < 4; ++p) {
      int idx = p * 1024 + t * 4;
      float4 xv = *(const float4*)(xr + idx);
      float4 sv = *(const float4*)(iscale + idx);
      float a0 = xv.x * sv.x, a1 = xv.y * sv.y, a2 = xv.z * sv.z, a3 = xv.w * sv.w;
      v[p * 4 + 0] = a0; v[p * 4 + 1] = a1; v[p * 4 + 2] = a2; v[p * 4 + 3] = a3;
      mx = fmaxf(mx, fmaxf(fmaxf(fabsf(a0), fabsf(a1)), fmaxf(fabsf(a2), fabsf(a3))));
    }
#pragma unroll
    for (int off = 32; off > 0; off >>= 1)
      mx = fmaxf(mx, __shfl_down(mx, off));
    __shared__ float rm[4];
    int wid = t >> 6, lane = t & 63;
    if (lane == 0) rm[wid] = mx;
    __syncthreads();
    float m = fmaxf(fmaxf(rm[0], rm[1]), fmaxf(rm[2], rm[3]));
    float inv = m > 0.f ? 127.f / m : 0.f;
    if (t == 0) alpha[row] = m * (1.f / 127.f);
#pragma unroll
    for (int p = 0; p < 4; ++p) {
      int idx = p * 1024 + t * 4;
      char4 q;
      int q0 = (int)rintf(v[p * 4 + 0] * inv);
      int q1 = (int)rintf(v[p * 4 + 1] * inv);
      int q2 = (int)rintf(v[p * 4 + 2] * inv);
      int q3 = (int)rintf(v[p * 4 + 3] * inv);
      q.x = (signed char)max(-127, min(127, q0));
      q.y = (signed char)max(-127, min(127, q1));
      q.z = (signed char)max(-127, min(127, q2));
      q.w = (signed char)max(-127, min(127, q3));
      *(char4*)(A + (size_t)row * GK + idx) = q;
    }
  } else {
    // prep_w: sign(w) in {-1,0,+1}, exact
    int e = ((b - PX_BLOCKS) * 256 + t) * 8;
    float4 v0 = *(const float4*)(w + e);
    float4 v1 = *(const float4*)(w + e + 4);
    auto sg = [](float v) -> signed char {
      return (signed char)((v > 0.f) - (v < 0.f));
    };
    union { signed char c[8]; unsigned long long u; } o;
    o.c[0] = sg(v0.x); o.c[1] = sg(v0.y); o.c[2] = sg(v0.z); o.c[3] = sg(v0.w);
    o.c[4] = sg(v1.x); o.c[5] = sg(v1.y); o.c[6] = sg(v1.z); o.c[7] = sg(v1.w);
    *(unsigned long long*)(Wb + e) = o.u;
  }
}

// -------------------- GEMM (i8): C[m][n] = alpha_m * sum_k qA[m][k]*sgnW[n][k] ----
// m97-SHAPED loop (zero inline asm): per K-step
//   { STAGE(t+1 -> buf^1); plain-C++ ds_reads; 32 MFMA; __syncthreads(); }
// The R5-R18 plateau mechanism (finally isolated): the manual
// `asm lgkmcnt(0)` before each MFMA cluster forced ALL reads to drain
// before the FIRST MFMA -> per-K-step time = serial sum of LDS-pipe +
// MFMA-pipe (measured 2690 cyc vs components 1307+1450). With plain C++
// reads the compiler emits COUNTED lgkmcnt(N) waits (m97 asm evidence:
// lgkmcnt(4/3/1/0) interleaved), so the first MFMA issues as soon as its
// own operands land and the remaining reads drain UNDER the MFMA stream.
// Correctness: __syncthreads() (compiler-inserted full vmcnt/lgkm drain +
// s_barrier) at step end makes STAGE(t+1) visible before step t+1 reads
// it, and orders step t's reads before step t+1's STAGE(t+2) overwrite
// of buf (WAR). The full drain is cheap: the stage was issued one whole
// K-step (~2300 cyc) earlier, >> 900-cyc HBM latency.
// Geometry/swizzle identical to R17/R18 (verified: 0 bank conflicts,
// absmax 0.1035): 256x256 tile, BK=64B, 512 threads (2M x 4N waves, wave
// tile 128x64, 8mi x 4ni frags), 16-B chunk c of row r holds k-group
// c^((r>>1)&3) (both-sides swizzle); i8 16x16x64 fragment row/col = l&15,
// k = (l>>4)*16 + e; C/D: col = lane&15, row = (lane>>4)*4 + r.
// Epilogue: h = alpha[row]*acc -> bf16 into 2nd half of each f32 row slot.
__device__ inline void gload16(const void* g, const void* l) {
  __builtin_amdgcn_global_load_lds(
      (const __attribute__((address_space(1))) void*)g,
      (__attribute__((address_space(3))) void*)l, 16, 0, 0);
}

__global__ __launch_bounds__(512, 2) void gemm_i8(
    const signed char* __restrict__ A, const signed char* __restrict__ Bm,
    const float* __restrict__ alpha, float* __restrict__ C) {
  extern __shared__ signed char lds8[];  // 2 slots x (A 16K + B 16K)

  // Square XCD chunking (R3-R18; FETCH ~98 MB on i8)
  int bid = blockIdx.x;            // 0..511
  int x = bid & 7, idx = bid >> 3;
  int brow = ((x & 3) << 3) | (idx & 7);   // 0..31
  int bcol = ((x >> 2) << 3) | (idx >> 3); // 0..15

  int tid = threadIdx.x, wid = tid >> 6, lane = tid & 63;
  int wm = wid & 1, wn = wid >> 1;         // 2M x 4N waves
  int lrow = lane & 15, lkhi = lane >> 4;

  const signed char* Ab = A + (size_t)(brow * BM) * GK;
  const signed char* Bb = Bm + (size_t)(bcol * BN) * GK;

  // read-side swizzled chunk (4 x 16-B chunks per 64-B row)
  int rchunk = lkhi ^ ((lrow >> 1) & 3);
  int avbase = (wm * 128 + lrow) * 64 + rchunk * 16;          // + mi*1024
  int bvbase = 16384 + (wn * 64 + lrow) * 64 + rchunk * 16;   // + ni*1024

  // stage-side: thread t covers row t>>2 (0..127), chunk t&3; source chunk
  // pre-permuted so LDS chunk c of row r holds k-group c^((r>>1)&3).
  // Row+128 (2nd issue) preserves (r>>1)&3, so the same gcol applies.
  int grow = tid >> 2;
  int gcol = ((tid & 3) ^ ((tid >> 3) & 3)) * 16;  // byte offset in 64-B window

  auto STAGE = [&](int kstep, int si) {
    const signed char* sA = Ab + (size_t)grow * GK + kstep * BK + gcol;
    const signed char* dA = lds8 + si * SLOT_BYTES + tid * 16;
    gload16(sA, dA);
    gload16(sA + (size_t)128 * GK, dA + 8192);
    const signed char* sB = Bb + (size_t)grow * GK + kstep * BK + gcol;
    gload16(sB, dA + 16384);
    gload16(sB + (size_t)128 * GK, dA + 16384 + 8192);
  };

  i32x4 acc[8][4] = {};

  // prologue: step 0 -> slot 0 (syncthreads drains vmcnt before the barrier)
  STAGE(0, 0);
  __syncthreads();

  for (int t = 0; t < NSTEP; ++t) {
    const signed char* sl = lds8 + (t & 1) * SLOT_BYTES;
    if (t + 1 < NSTEP) STAGE(t + 1, (t + 1) & 1);

    // plain C++ LDS reads — compiler emits counted lgkmcnt and interleaves
    // the MFMAs below with the in-flight reads.
    i32x4 af[8], bf[4];
#pragma unroll
    for (int mi = 0; mi < 8; ++mi)
      af[mi] = *(const i32x4*)(sl + avbase + mi * 1024);
#pragma unroll
    for (int ni = 0; ni < 4; ++ni)
      bf[ni] = *(const i32x4*)(sl + bvbase + ni * 1024);

#pragma unroll
    for (int mi = 0; mi < 8; ++mi)
#pragma unroll
      for (int ni = 0; ni < 4; ++ni)
        acc[mi][ni] = __builtin_amdgcn_mfma_i32_16x16x64_i8(
            af[mi], bf[ni], acc[mi][ni], 0, 0, 0);

    // one barrier per K-step: makes STAGE(t+1) visible for step t+1 and
    // orders this step's reads before STAGE(t+2)'s overwrite (WAR).
    __syncthreads();
  }

  // epilogue: h = alpha[row]*acc as bf16 into 2nd half of each f32 row slot.
  // C/D layout: col = lane&15, row = (lane>>4)*4 + r
  int crow0 = brow * BM + wm * 128;
  int ccol0 = bcol * BN + wn * 64;
  char* Cb = (char*)C;
#pragma unroll
  for (int mi = 0; mi < 8; ++mi)
#pragma unroll
    for (int ni = 0; ni < 4; ++ni) {
      int col = ccol0 + ni * 16 + lrow;
#pragma unroll
      for (int r = 0; r < 4; ++r) {
        int row = crow0 + mi * 16 + lkhi * 4 + r;
        float h = alpha[row] * (float)acc[mi][ni][r];
        *(__bf16*)(Cb + (size_t)row * 16384 + 8192 + col * 2) = (__bf16)h;
      }
    }
}

// ---------- fused out_scale/bias + LayerNorm: bf16 h (2nd half-slot) -> f32 ----------
__global__ __launch_bounds__(256) void ln_fuse(
    float* __restrict__ out, const float* __restrict__ os,
    const float* __restrict__ bs, const float* __restrict__ g,
    const float* __restrict__ be) {
  constexpr int N = GN;  // 4096
  int row = blockIdx.x;
  const __bf16* hr = (const __bf16*)((const char*)out + (size_t)row * 16384 + 8192);
  float* orow = out + (size_t)row * N;
  int t = threadIdx.x;

  float v[16];
  float sum = 0.f, ssq = 0.f;
#pragma unroll
  for (int c = 0; c < 2; ++c) {
    int idx = c * 2048 + t * 8;       // 8 bf16 per chunk, 2 chunks/thread
    bf16x8 hv = *(const bf16x8*)(hr + idx);
    float4 s0 = *(const float4*)(os + idx);
    float4 s1 = *(const float4*)(os + idx + 4);
    float4 b0 = *(const float4*)(bs + idx);
    float4 b1 = *(const float4*)(bs + idx + 4);
#pragma unroll
    for (int j = 0; j < 4; ++j) {
      float a = (float)hv[j] * (&s0.x)[j] + (&b0.x)[j];
      v[c * 8 + j] = a;
      sum += a; ssq += a * a;
    }
#pragma unroll
    for (int j = 0; j < 4; ++j) {
      float a = (float)hv[4 + j] * (&s1.x)[j] + (&b1.x)[j];
      v[c * 8 + 4 + j] = a;
      sum += a; ssq += a * a;
    }
  }

  // wave64 reduce
#pragma unroll
  for (int off = 32; off > 0; off >>= 1) {
    sum += __shfl_down(sum, off);
    ssq += __shfl_down(ssq, off);
  }
  __shared__ float rs[8];
  int wid = t >> 6, lane = t & 63;
  if (lane == 0) { rs[wid] = sum; rs[4 + wid] = ssq; }
  __syncthreads();   // also separates all h reads from the in-place writes
  sum = rs[0] + rs[1] + rs[2] + rs[3];
  ssq = rs[4] + rs[5] + rs[6] + rs[7];

  float mean = sum * (1.f / N);
  float var = ssq * (1.f / N) - mean * mean;
  float rstd = rsqrtf(var + 1e-5f);

#pragma unroll
  for (int c = 0; c < 2; ++c) {
    int idx = c * 2048 + t * 8;
    float4 g0 = *(const float4*)(g + idx);
    float4 g1 = *(const float4*)(g + idx + 4);
    float4 e0 = *(const float4*)(be + idx);
    float4 e1 = *(const float4*)(be + idx + 4);
    float4 o0, o1;
#pragma unroll
    for (int j = 0; j < 4; ++j) {
      (&o0.x)[j] = (v[c * 8 + j] - mean) * rstd * (&g0.x)[j] + (&e0.x)[j];
      (&o1.x)[j] = (v[c * 8 + 4 + j] - mean) * rstd * (&g1.x)[j] + (&e1.x)[j];
    }
    *(float4*)(orow + idx) = o0;
    *(float4*)(orow + idx + 4) = o1;
  }
}

extern "C" void kernel_launch(void* const* d_in, const int* in_sizes, int n_in,
                              void* d_out, int out_size, void* d_ws, size_t ws_size,
                              hipStream_t stream) {
  const float* x      = (const float*)d_in[0];  // [4,2048,4096]
  const float* w      = (const float*)d_in[1];  // [4096,4096]
  const float* iscale = (const float*)d_in[2];  // [4096]
  const float* oscale = (const float*)d_in[3];  // [4096]
  const float* bias   = (const float*)d_in[4];  // [4096]
  const float* gamma  = (const float*)d_in[5];  // [4096]
  const float* beta   = (const float*)d_in[6];  // [4096]
  float* out = (float*)d_out;                   // [8192,4096] f32

  signed char* Ai8 = (signed char*)d_ws;                         // 33.6 MB
  signed char* Wi8 = (signed char*)d_ws + (size_t)GM * GK;       // 16.8 MB
  float* alpha = (float*)((char*)d_ws + (size_t)GM * GK + (size_t)GN * GK);  // 32 KB

  (void)hipFuncSetAttribute((const void*)gemm_i8,
                            hipFuncAttributeMaxDynamicSharedMemorySize, LDS_BYTES);

  prep_fused_i8<<<PX_BLOCKS + PW_BLOCKS, 256, 0, stream>>>(x, iscale, w, Ai8,
                                                           Wi8, alpha);
  gemm_i8<<<(GM / BM) * (GN / BN), 512, LDS_BYTES, stream>>>(Ai8, Wi8, alpha, out);
  ln_fuse<<<GM, 256, 0, stream>>>(out, oscale, bias, gamma, beta);
}